// Round 1
// baseline (548.953 us; speedup 1.0000x reference)
//
#include <hip/hip_runtime.h>

#define TT 512
#define II 10
#define HH 32
#define LOG2E 1.44269504088896340736f

typedef __attribute__((ext_vector_type(8))) short bf16x8;   // MFMA A/B frag (4 VGPRs)
typedef __attribute__((ext_vector_type(4))) float f32x4;    // MFMA C/D frag
typedef __attribute__((ext_vector_type(4))) int   i32x4;

#define MFMA(A, B, C) __builtin_amdgcn_mfma_f32_16x16x32_bf16((A), (B), (C), 0, 0, 0)

static __device__ __forceinline__ float frcp(float v) { return __builtin_amdgcn_rcpf(v); }
static __device__ __forceinline__ float fexp2(float v) { return __builtin_amdgcn_exp2f(v); }

static __device__ __forceinline__ short bf16rne(float f) {
    unsigned u = __builtin_bit_cast(unsigned, f);
    u += 0x7fffu + ((u >> 16) & 1u);
    return (short)(u >> 16);
}
// {bf16(a) lo, bf16(b) hi} by truncation (validated in R7): 1 v_perm_b32
static __device__ __forceinline__ unsigned pk2(float a, float b) {
    return __builtin_amdgcn_perm(__builtin_bit_cast(unsigned, b),
                                 __builtin_bit_cast(unsigned, a), 0x07060302u);
}
// same but round-to-nearest (h feeds 512 recurrent steps; avoid trunc bias)
static __device__ __forceinline__ unsigned pkh(float a, float b) {
    return __builtin_amdgcn_perm(__builtin_bit_cast(unsigned, b) + 0x8000u,
                                 __builtin_bit_cast(unsigned, a) + 0x8000u, 0x07060302u);
}

// SOLO-WAVE MFMA LSTM: one 64-thread wave owns one 16-batch-row chain,
// computing ALL 8 gate-row subtiles itself. Key property of the K-permutation
// pi(q*8+j) = 4j+q: consumer lane (n,q) needs B_h element j = h[unit 4j+q,
// batch n] -- and lane (n,q) of subtile s=j PRODUCES h[unit 4s+q, batch n].
// Producer set == consumer set, LANE-LOCAL. Therefore: no LDS, no barrier,
// no shuffle, no cross-wave exchange. The per-step s_barrier + compiler's
// s_waitcnt vmcnt(0) drain (which serialized the x prefetch every step in the
// 4-wave version) is gone entirely; x prefetch (distance 2) overlaps the
// 8-unit epilogue. C-frag of subtile s at lane (n,q): batch n, unit 4s+q,
// 4 gates in regs r=0..3 (G = 16s + 4q + r = unit*4 + gate).
// Weights pre-scaled by log2e (g-gate 2*log2e): unified rcp(1+exp2(-s))
// activations; bias rides the x-MFMA at k=10 with B=1.0.
extern "C" __global__ __launch_bounds__(64)
__attribute__((amdgpu_waves_per_eu(1)))
void lstm_mfma(const float* __restrict__ x,
               const float* __restrict__ h0,
               const float* __restrict__ c0,
               const float* __restrict__ W_ih,
               const float* __restrict__ W_hh,
               const float* __restrict__ b_ih,
               const float* __restrict__ b_hh,
               const float* __restrict__ W_lin,
               const float* __restrict__ b_lin,
               float* __restrict__ out)
{
    const int lane = threadIdx.x & 63;
    const int n    = lane & 15;        // batch col (and A-frag row m)
    const int q    = lane >> 4;        // k-chunk / C row-group
    const int R    = blockIdx.x * 16;

    // ---- A-frags (weights), one-time, all 8 subtiles. A[m=n][k=q*8+j]. ----
    // gate row in subtile s: G = 16s+n -> unit = 4s+(n>>2), gate = n&3.
    // h-part column = pi(k) = 4j+q. x-part column = k (unpermuted).
    const int   gate = n & 3;
    const float sc   = (gate == 2) ? 2.0f * LOG2E : LOG2E;

    bf16x8 Ah[8], Ax[8];
    float  c[8], wl[8], h[8];
    #pragma unroll
    for (int s = 0; s < 8; ++s) {
        const int unitm = 4 * s + (n >> 2);
        const int Wr    = gate * HH + unitm;
        #pragma unroll
        for (int j = 0; j < 8; ++j) {
            Ah[s][j] = bf16rne(W_hh[Wr * HH + 4 * j + q] * sc);
            const int k = q * 8 + j;
            float xv = 0.0f;
            if (k < II)       xv = W_ih[Wr * II + k] * sc;
            else if (k == II) xv = (b_ih[Wr] + b_hh[Wr]) * sc;   // bias (B has 1.0 at k=10)
            Ax[s][j] = bf16rne(xv);
        }
        const int u = 4 * s + q;                // unit this lane OWNS in subtile s
        c[s]  = c0[(R + n) * HH + u];
        wl[s] = W_lin[u];
    }

    // B_h dwords: dword d = pair (unit 8d+q, unit 8d+4+q) = (s=2d, s=2d+1)
    i32x4 Bh;
    #pragma unroll
    for (int d = 0; d < 4; ++d)
        Bh[d] = (int)pkh(h0[(R + n) * HH + 8 * d + q],
                         h0[(R + n) * HH + 8 * d + 4 + q]);

    // x: lane holds its batch row's 10 floats; two reg sets -> prefetch dist 2
    const float* xp = x + (size_t)(R + n) * (TT * II);
    float2 e0 = *(const float2*)(xp + 0), e1 = *(const float2*)(xp + 2),
           e2 = *(const float2*)(xp + 4), e3 = *(const float2*)(xp + 6),
           e4 = *(const float2*)(xp + 8);
    float2 o0 = *(const float2*)(xp + II + 0), o1 = *(const float2*)(xp + II + 2),
           o2 = *(const float2*)(xp + II + 4), o3 = *(const float2*)(xp + II + 6),
           o4 = *(const float2*)(xp + II + 8);

    const bool q0 = (q == 0), q1 = (q == 1);
    const f32x4 z4 = {0.0f, 0.0f, 0.0f, 0.0f};

    // One timestep: consume x regs l0..l4, prefetch row pf into them (dist 2),
    // update c[], h[], Bh. Entirely register-resident; zero sync.
    auto STEP = [&](float2& l0, float2& l1, float2& l2, float2& l3, float2& l4,
                    int pf) {
        // B_x: k=q*8+j -> q0:{x0..x7}, q1:{x8,x9,1.0,0..}, q2/q3: 0
        const unsigned d0 = q0 ? pk2(l0.x, l0.y) : (q1 ? pk2(l4.x, l4.y) : 0u);
        const unsigned d1 = q0 ? pk2(l1.x, l1.y) : (q1 ? 0x00003F80u : 0u);
        const unsigned d2 = q0 ? pk2(l2.x, l2.y) : 0u;
        const unsigned d3 = q0 ? pk2(l3.x, l3.y) : 0u;
        const bf16x8 Bx = __builtin_bit_cast(bf16x8, (i32x4){(int)d0, (int)d1, (int)d2, (int)d3});

        f32x4 acc[8];
        #pragma unroll
        for (int s = 0; s < 8; ++s) acc[s] = MFMA(Ax[s], Bx, z4);   // x part first

        {   // distance-2 prefetch (no barrier -> genuinely overlaps epilogue)
            const float* px = xp + (size_t)pf * II;
            l0 = *(const float2*)(px + 0); l1 = *(const float2*)(px + 2);
            l2 = *(const float2*)(px + 4); l3 = *(const float2*)(px + 6);
            l4 = *(const float2*)(px + 8);
        }

        const bf16x8 BhF = __builtin_bit_cast(bf16x8, Bh);
        #pragma unroll
        for (int s = 0; s < 8; ++s) acc[s] = MFMA(Ah[s], BhF, acc[s]);

        // epilogue: 8 independent unit chains (ILP) -> unified activations
        #pragma unroll
        for (int s = 0; s < 8; ++s) {
            const float ri = frcp(1.0f + fexp2(-acc[s][0]));
            const float rf = frcp(1.0f + fexp2(-acc[s][1]));
            const float rg = frcp(1.0f + fexp2(-acc[s][2]));
            const float ro = frcp(1.0f + fexp2(-acc[s][3]));
            c[s] = rf * c[s] + ri * (2.0f * rg - 1.0f);
            const float rt = frcp(1.0f + fexp2(c[s] * (-2.0f * LOG2E)));
            h[s] = ro * (2.0f * rt - 1.0f);
        }
        // next step's B_h, packed lane-locally (the zero-exchange property)
        #pragma unroll
        for (int d = 0; d < 4; ++d) Bh[d] = (int)pkh(h[2 * d], h[2 * d + 1]);
    };

    #pragma unroll 1
    for (int t = 0; t < TT; t += 2) {
        const int pfe = (t + 2 < TT) ? t + 2 : TT - 1;
        const int pfo = (t + 3 < TT) ? t + 3 : TT - 1;
        STEP(e0, e1, e2, e3, e4, pfe);
        STEP(o0, o1, o2, o3, o4, pfo);
    }

    // out[R+n] = sum_u h[n][u]*W_lin[u] + b_lin: lane holds units 4s+q;
    // reduce over q-groups with 2 shuffles (single wave -> no LDS needed)
    float p = 0.0f;
    #pragma unroll
    for (int s = 0; s < 8; ++s) p += h[s] * wl[s];
    p += __shfl_xor(p, 16);
    p += __shfl_xor(p, 32);
    if (lane < 16) out[R + lane] = p + b_lin[0];
}

extern "C" void kernel_launch(void* const* d_in, const int* in_sizes, int n_in,
                              void* d_out, int out_size, void* d_ws, size_t ws_size,
                              hipStream_t stream) {
    const float* x     = (const float*)d_in[0];
    const float* h0    = (const float*)d_in[1];
    const float* c0    = (const float*)d_in[2];
    const float* W_ih  = (const float*)d_in[3];
    const float* W_hh  = (const float*)d_in[4];
    const float* b_ih  = (const float*)d_in[5];
    const float* b_hh  = (const float*)d_in[6];
    const float* W_lin = (const float*)d_in[7];
    const float* b_lin = (const float*)d_in[8];
    float* out = (float*)d_out;

    const int B = in_sizes[1] / HH;   // 4096
    dim3 grid(B / 16), block(64);     // 1 wave per block = 1 independent chain
    lstm_mfma<<<grid, block, 0, stream>>>(x, h0, c0, W_ih, W_hh, b_ih, b_hh, W_lin, b_lin, out);
}

// Round 2
// 329.316 us; speedup vs baseline: 1.6669x; 1.6669x over previous
//
#include <hip/hip_runtime.h>

#define TT 512
#define II 10
#define HH 32
#define LOG2E 1.44269504088896340736f

typedef __attribute__((ext_vector_type(8))) short bf16x8;   // MFMA A/B frag (4 VGPRs)
typedef __attribute__((ext_vector_type(4))) float f32x4;    // MFMA C/D frag
typedef __attribute__((ext_vector_type(4))) int   i32x4;

#define MFMA(A, B, C) __builtin_amdgcn_mfma_f32_16x16x32_bf16((A), (B), (C), 0, 0, 0)

static __device__ __forceinline__ float frcp(float v) { return __builtin_amdgcn_rcpf(v); }
static __device__ __forceinline__ float fexp2(float v) { return __builtin_amdgcn_exp2f(v); }

static __device__ __forceinline__ short bf16rne(float f) {
    unsigned u = __builtin_bit_cast(unsigned, f);
    u += 0x7fffu + ((u >> 16) & 1u);
    return (short)(u >> 16);
}
// {bf16(a) lo, bf16(b) hi} by truncation (validated in R7): 1 v_perm_b32
static __device__ __forceinline__ unsigned pk2(float a, float b) {
    return __builtin_amdgcn_perm(__builtin_bit_cast(unsigned, b),
                                 __builtin_bit_cast(unsigned, a), 0x07060302u);
}
// same but round-to-nearest (h feeds 512 recurrent steps; avoid trunc bias)
static __device__ __forceinline__ unsigned pkh(float a, float b) {
    return __builtin_amdgcn_perm(__builtin_bit_cast(unsigned, b) + 0x8000u,
                                 __builtin_bit_cast(unsigned, a) + 0x8000u, 0x07060302u);
}

// MFMA LSTM, exchange-minimal layout, 4 waves / 16 batch rows per block.
// Same layout algebra as the 253us version (K-permutation pi(q*8+j)=4j+q;
// wave m's lane (n,q) produces exactly the h-pair dword that consumer lanes
// read as b_m), with ONE structural change:
//
//   __syncthreads()  -->  s_waitcnt lgkmcnt(0) ; s_barrier
//
// __syncthreads' workgroup fence forces the compiler to emit
// s_waitcnt vmcnt(0) before s_barrier, draining the x prefetch
// (HBM/L3 latency ~500-900cy) into the critical path EVERY step -- that
// drain, not the exchange, was the dominant stall (MfmaUtil 5.4%,
// VALUBusy 30%, ~900cy/step of overhead). The LDS exchange only needs
// lgkm ordering: global x loads are read-only with no cross-wave hazard,
// so they may legally stay in flight across the barrier. Prefetch is
// upgraded to distance 2 (two register sets) for ~2 steps of latency cover.
extern "C" __global__ __launch_bounds__(256)
__attribute__((amdgpu_waves_per_eu(1)))
void lstm_mfma(const float* __restrict__ x,
               const float* __restrict__ h0,
               const float* __restrict__ c0,
               const float* __restrict__ W_ih,
               const float* __restrict__ W_hh,
               const float* __restrict__ b_ih,
               const float* __restrict__ b_hh,
               const float* __restrict__ W_lin,
               const float* __restrict__ b_lin,
               float* __restrict__ out)
{
    __shared__ int   hx[2][4][16][4];   // [buf][producer-wave][n][q] bf16 pair
    __shared__ float plds[64];

    const int tid  = threadIdx.x;
    const int w    = tid >> 6;
    const int lane = tid & 63;
    const int n    = lane & 15;        // batch col (and A-frag row m)
    const int q    = lane >> 4;        // k-chunk / C row-group
    const int R    = blockIdx.x * 16;

    // ---- A-frags (weights), one-time. A[m=n][k=q*8+j]. ----
    // gate row in subtile s: G = 16s+n -> unit = 4s+(n>>2), gate = n&3.
    // h-part column = pi(k) = 4j+q. x-part column = k (unpermuted).
    const int   gate = n & 3;
    const float sc   = (gate == 2) ? 2.0f * LOG2E : LOG2E;
    bf16x8 AhA, AhB, AxA, AxB;
    #pragma unroll
    for (int st = 0; st < 2; ++st) {
        const int s     = 2 * w + st;
        const int unitm = 4 * s + (n >> 2);
        const int Wr    = gate * HH + unitm;
        bf16x8 ah, ax;
        #pragma unroll
        for (int j = 0; j < 8; ++j) {
            ah[j] = bf16rne(W_hh[Wr * HH + 4 * j + q] * sc);
            const int k = q * 8 + j;
            float xv = 0.0f;
            if (k < II)       xv = W_ih[Wr * II + k] * sc;
            else if (k == II) xv = (b_ih[Wr] + b_hh[Wr]) * sc;   // bias (B has 1.0 at k=10)
            ax[j] = bf16rne(xv);
        }
        if (st == 0) { AhA = ah; AxA = ax; } else { AhB = ah; AxB = ax; }
    }

    const int uA = 8 * w + q, uB = uA + 4;     // units this lane owns (batch n)
    float cA = c0[(R + n) * HH + uA];
    float cB = c0[(R + n) * HH + uB];
    const float wlA = W_lin[uA], wlB = W_lin[uB];

    // init h -> buf 0 (packed pair, exactly what consumers expect)
    hx[0][w][n][q] = (int)pkh(h0[(R + n) * HH + uA], h0[(R + n) * HH + uB]);
    __syncthreads();   // one-time full sync is fine

    // x: lane holds its batch row's 10 floats; two reg sets -> prefetch dist 2
    const float* xp = x + (size_t)(R + n) * (TT * II);
    float2 e0 = *(const float2*)(xp + 0), e1 = *(const float2*)(xp + 2),
           e2 = *(const float2*)(xp + 4), e3 = *(const float2*)(xp + 6),
           e4 = *(const float2*)(xp + 8);
    float2 o0 = *(const float2*)(xp + II + 0), o1 = *(const float2*)(xp + II + 2),
           o2 = *(const float2*)(xp + II + 4), o3 = *(const float2*)(xp + II + 6),
           o4 = *(const float2*)(xp + II + 8);

    const bool q0 = (q == 0), q1 = (q == 1);
    const f32x4 z4 = {0.0f, 0.0f, 0.0f, 0.0f};
    float hA = 0.0f, hB = 0.0f;

    // One timestep (rb = t&1 as a compile-time constant after inlining).
    auto STEP = [&](int rb, float2& l0, float2& l1, float2& l2, float2& l3,
                    float2& l4, int pf) {
        // B_h dwords: producer-wave m = 0..3 at stride 256B (2x ds_read2_b32)
        const int b0 = hx[rb][0][n][q];
        const int b1 = hx[rb][1][n][q];
        const int b2 = hx[rb][2][n][q];
        const int b3 = hx[rb][3][n][q];

        // B_x: k=q*8+j -> q0:{x0..x7}, q1:{x8,x9,1.0,0..}, q2/q3: 0
        const unsigned d0 = q0 ? pk2(l0.x, l0.y) : (q1 ? pk2(l4.x, l4.y) : 0u);
        const unsigned d1 = q0 ? pk2(l1.x, l1.y) : (q1 ? 0x00003F80u : 0u);
        const unsigned d2 = q0 ? pk2(l2.x, l2.y) : 0u;
        const unsigned d3 = q0 ? pk2(l3.x, l3.y) : 0u;
        const bf16x8 Bx = __builtin_bit_cast(bf16x8, (i32x4){(int)d0, (int)d1, (int)d2, (int)d3});

        f32x4 accA = MFMA(AxA, Bx, z4);     // x part first: independent of h
        f32x4 accB = MFMA(AxB, Bx, z4);

        {   // distance-2 prefetch; stays in flight across the raw barrier
            const float* px = xp + (size_t)pf * II;
            l0 = *(const float2*)(px + 0); l1 = *(const float2*)(px + 2);
            l2 = *(const float2*)(px + 4); l3 = *(const float2*)(px + 6);
            l4 = *(const float2*)(px + 8);
        }

        const bf16x8 Bh = __builtin_bit_cast(bf16x8, (i32x4){b0, b1, b2, b3});
        accA = MFMA(AhA, Bh, accA);
        accB = MFMA(AhB, Bh, accB);

        // epilogue: gates are the 4 C regs (pre-scaled) -> unified activation
        {
            const float ri = frcp(1.0f + fexp2(-accA[0]));
            const float rf = frcp(1.0f + fexp2(-accA[1]));
            const float rg = frcp(1.0f + fexp2(-accA[2]));
            const float ro = frcp(1.0f + fexp2(-accA[3]));
            cA = rf * cA + ri * (2.0f * rg - 1.0f);
            const float rt = frcp(1.0f + fexp2(cA * (-2.0f * LOG2E)));
            hA = ro * (2.0f * rt - 1.0f);
        }
        {
            const float ri = frcp(1.0f + fexp2(-accB[0]));
            const float rf = frcp(1.0f + fexp2(-accB[1]));
            const float rg = frcp(1.0f + fexp2(-accB[2]));
            const float ro = frcp(1.0f + fexp2(-accB[3]));
            cB = rf * cB + ri * (2.0f * rg - 1.0f);
            const float rt = frcp(1.0f + fexp2(cB * (-2.0f * LOG2E)));
            hB = ro * (2.0f * rt - 1.0f);
        }
        hx[1 - rb][w][n][q] = (int)pkh(hA, hB);   // next step's B_h dword

        // LDS-only sync: drain lgkm (write committed + our reads landed),
        // then raw barrier. vmcnt (x prefetch) intentionally NOT drained --
        // this is the entire point vs __syncthreads.
        asm volatile("s_waitcnt lgkmcnt(0)" ::: "memory");
        __builtin_amdgcn_s_barrier();
        asm volatile("" ::: "memory");
    };

    #pragma unroll 1
    for (int t = 0; t < TT; t += 2) {
        const int pfe = (t + 2 < TT) ? t + 2 : TT - 1;
        const int pfo = (t + 3 < TT) ? t + 3 : TT - 1;
        STEP(0, e0, e1, e2, e3, e4, pfe);
        STEP(1, o0, o1, o2, o3, o4, pfo);
    }

    // out[R+n] = sum_u h[n][u]*W_lin[u] + b_lin: reduce over q-groups then waves
    float p = hA * wlA + hB * wlB;
    p += __shfl_xor(p, 16);
    p += __shfl_xor(p, 32);
    if (q == 0) plds[w * 16 + n] = p;
    __syncthreads();
    if (tid < 16) {
        out[R + tid] = plds[tid] + plds[16 + tid] + plds[32 + tid] + plds[48 + tid] + b_lin[0];
    }
}

extern "C" void kernel_launch(void* const* d_in, const int* in_sizes, int n_in,
                              void* d_out, int out_size, void* d_ws, size_t ws_size,
                              hipStream_t stream) {
    const float* x     = (const float*)d_in[0];
    const float* h0    = (const float*)d_in[1];
    const float* c0    = (const float*)d_in[2];
    const float* W_ih  = (const float*)d_in[3];
    const float* W_hh  = (const float*)d_in[4];
    const float* b_ih  = (const float*)d_in[5];
    const float* b_hh  = (const float*)d_in[6];
    const float* W_lin = (const float*)d_in[7];
    const float* b_lin = (const float*)d_in[8];
    float* out = (float*)d_out;

    const int B = in_sizes[1] / HH;   // 4096
    dim3 grid(B / 16), block(256);    // 16 rows/block, 4 waves, 1 block/CU
    lstm_mfma<<<grid, block, 0, stream>>>(x, h0, c0, W_ih, W_hh, b_ih, b_hh, W_lin, b_lin, out);
}